// Round 2
// 9914.700 us; speedup vs baseline: 1.0326x; 1.0326x over previous
//
#include <hip/hip_runtime.h>
#include <math.h>

#define B 32
#define E 512
#define CTXD 512
#define H 1024
#define G4 4096      // 4*H
#define V 32000
#define T 64
#define LDW 1024     // row length (floats) of every weight matrix here
#define START_TOK 1

// ---------------- workspace layout (float offsets) ----------------
#define OFF_GCTX   0L          // [B][G4]  ctx@Wih0[:,512:] + b_ih0 + b_hh0
#define OFF_H0     131072L     // [B][H]
#define OFF_C0     163840L
#define OFF_H1     196608L
#define OFF_C1     229376L
#define OFF_PART0  262144L     // [6][B][G4] layer0 K-split partials
#define OFF_PART1  1048576L    // [8][B][G4] layer1 K-split partials
#define OFF_BSUM1  2097152L    // [G4]  b_ih1 + b_hh1
#define OFF_SUMS   2101248L    // [T][B] float softmax denominators
#define OFF_AMAX   2103296L    // [T][B] u64 packed (exp_bits<<32)|(~v)

// ------------------------------------------------------------------
// Shared block for the skinny GEMM. W tile 64 rows x 64 k staged via
// global_load_lds with XOR-swizzled SOURCE address (LDS dest linear —
// rule: gload_lds writes base+lane*16 only); read side applies the
// same XOR so lanes spread over all 32 banks. X tile 32 x 64 linear;
// X reads are wave-uniform broadcasts (no conflicts). 48.5 KB.
// ------------------------------------------------------------------
struct Smem {
  float4 Wb[2][1024];   // [buf][row*16 + unit]   unit u holds global unit u^(row&7)
  float4 Xb[2][512];    // [buf][b*16 + unit]
  const float* srow[B];
};

__device__ __forceinline__ void gload16(const float* g, void* l)
{
  __builtin_amdgcn_global_load_lds(
      (const __attribute__((address_space(1))) void*)g,
      (__attribute__((address_space(3))) void*)l,
      16, 0, 0);
}

// Block: 256 threads = 4 waves. Tile: 64 j x 32 b, K in 64-chunks.
// Wave w owns b in [8w,8w+8); lane jj owns j = j0+jj; acc[8] over b.
// 2-phase: STAGE(next) -> compute(cur) -> __syncthreads() (single
// barrier per chunk; its vmcnt(0) drain happens AFTER compute, so the
// prefetch had the whole compute phase to land).
__device__ __forceinline__ void gemm64(
    const float* __restrict__ W, int wcol, int j0, int xcol, int klen,
    int tid, Smem& sm, float (&acc)[8])
{
  const int jj  = tid & 63;
  const int bg8 = (tid >> 6) << 3;
  const int swz = jj & 7;

  // staging sources (advance by kc only)
  const float* wsrc[4];
#pragma unroll
  for (int i = 0; i < 4; i++) {
    int r = (tid >> 4) + (i << 4);           // 0..63
    wsrc[i] = W + (long)(j0 + r) * LDW
                + (wcol + (((tid & 15) ^ (r & 7)) << 2));  // pre-swizzled src
  }
  const float* xsrc[2];
#pragma unroll
  for (int i = 0; i < 2; i++) {
    int L = tid + (i << 8);                  // 0..511
    xsrc[i] = sm.srow[L >> 4] + xcol + ((L & 15) << 2);
  }

  auto STAGE = [&](int buf, int kc) {
#pragma unroll
    for (int i = 0; i < 4; i++)
      gload16(wsrc[i] + kc, &sm.Wb[buf][tid + (i << 8)]);
#pragma unroll
    for (int i = 0; i < 2; i++)
      gload16(xsrc[i] + kc, &sm.Xb[buf][tid + (i << 8)]);
  };

  const int nt = klen >> 6;
  STAGE(0, 0);
  __syncthreads();                            // stage(0) landed everywhere
#pragma unroll 1
  for (int t = 0; t < nt; t++) {
    const int cur = t & 1;
    if (t + 1 < nt) STAGE(cur ^ 1, (t + 1) << 6);

    const float4* wrow = &sm.Wb[cur][jj << 4];
    const float4* xrow = &sm.Xb[cur][bg8 << 4];
#pragma unroll
    for (int kq = 0; kq < 16; kq++) {
      const float4 w4 = wrow[kq ^ swz];
#pragma unroll
      for (int g = 0; g < 8; g++) {
        const float4 xv = xrow[(g << 4) + kq];
        acc[g] = fmaf(w4.x, xv.x, acc[g]);
        acc[g] = fmaf(w4.y, xv.y, acc[g]);
        acc[g] = fmaf(w4.z, xv.z, acc[g]);
        acc[g] = fmaf(w4.w, xv.w, acc[g]);
      }
    }
    __syncthreads();   // vmcnt(0)+lgkmcnt(0)+barrier: next stage landed,
                       // all reads of buf[cur] complete
  }
}

// ---------------- init: zero states/sums/amax, bsum1 ----------------
__global__ void init_kernel(float* __restrict__ ws,
                            const float* __restrict__ bih1,
                            const float* __restrict__ bhh1)
{
  int i = blockIdx.x * 256 + threadIdx.x;      // 65536 threads
  for (int k = i; k < 131072; k += 65536) ws[OFF_H0 + k] = 0.f;
  if (i < 4096) ws[OFF_BSUM1 + i] = bih1[i] + bhh1[i];
  if (i < 2048) ws[OFF_SUMS + i] = 0.f;
  if (i < 4096) ws[OFF_AMAX + i] = 0.f;        // u64 zeros
}

// ---------------- gctx = ctx @ Wih0[:,512:].T + biases (once) ----------------
__global__ __launch_bounds__(256)
void gctx_kernel(float* __restrict__ ws,
                 const float* __restrict__ ctx,
                 const float* __restrict__ Wih0,
                 const float* __restrict__ bih0,
                 const float* __restrict__ bhh0)
{
  __shared__ Smem sm;
  const int tid = threadIdx.x;
  const int j0  = blockIdx.x * 64;             // grid 64
  if (tid < B) sm.srow[tid] = ctx + tid * CTXD;
  __syncthreads();

  float acc[8] = {};
  gemm64(Wih0, /*wcol=*/E, j0, /*xcol=*/0, /*klen=*/CTXD, tid, sm, acc);

  const int jj = tid & 63, bg8 = (tid >> 6) << 3;
  const float bs = bih0[j0 + jj] + bhh0[j0 + jj];
#pragma unroll
  for (int g = 0; g < 8; g++)
    ws[OFF_GCTX + (long)(bg8 + g) * G4 + j0 + jj] = acc[g] + bs;
}

// ---------------- LSTM gate GEMM partials (both layers) ----------------
__global__ __launch_bounds__(256)
void lstm_gemm(int layer, int t,
               const float* __restrict__ Wih,
               const float* __restrict__ Whh,
               const float* __restrict__ emb,
               float* __restrict__ ws)
{
  __shared__ Smem sm;
  const int tid = threadIdx.x;
  const int c   = blockIdx.y;
  const int j0  = blockIdx.x * 64;             // grid (64, 6|8)

  const float* W;
  int wcol, xcol;
  if (layer == 0) {
    if (c < 2) { W = Wih; wcol = c * 256; xcol = wcol; }
    else       { W = Whh; wcol = (c - 2) * 256; xcol = wcol; }
  } else {
    if (c < 4) { W = Wih; wcol = c * 256; xcol = wcol; }
    else       { W = Whh; wcol = (c - 4) * 256; xcol = wcol; }
  }
  if (tid < B) {
    const float* r;
    if (layer == 0 && c < 2) {
      int tok;
      if (t == 0) tok = START_TOK;
      else {
        unsigned long long p =
            ((const unsigned long long*)(ws + OFF_AMAX))[(long)(t - 1) * B + tid];
        tok = (int)(0xFFFFFFFFu - (unsigned)(p & 0xFFFFFFFFull));
      }
      r = emb + (long)tok * E;
    } else if (layer == 0) {
      r = ws + OFF_H0 + (long)tid * H;
    } else {
      r = ws + (c < 4 ? OFF_H0 : OFF_H1) + (long)tid * H;
    }
    sm.srow[tid] = r;
  }
  __syncthreads();

  float acc[8] = {};
  gemm64(W, wcol, j0, xcol, /*klen=*/256, tid, sm, acc);

  const int jj = tid & 63, bg8 = (tid >> 6) << 3;
  float* part = ws + (layer == 0 ? OFF_PART0 : OFF_PART1) + (long)c * B * G4;
#pragma unroll
  for (int g = 0; g < 8; g++)
    part[(long)(bg8 + g) * G4 + j0 + jj] = acc[g];
}

// ---------------- cell updates ----------------
__global__ void cell0_kernel(float* __restrict__ ws)
{
  int idx = blockIdx.x * 256 + threadIdx.x;   // 0..32767
  int b = idx >> 10, h = idx & 1023;
  const float* gc = ws + OFF_GCTX + (long)b * G4;
  float gi = gc[h], gf = gc[h + 1024], gg = gc[h + 2048], go = gc[h + 3072];
#pragma unroll
  for (int c = 0; c < 6; c++) {
    const float* p = ws + OFF_PART0 + ((long)c * B + b) * G4;
    gi += p[h]; gf += p[h + 1024]; gg += p[h + 2048]; go += p[h + 3072];
  }
  float i_ = 1.f / (1.f + expf(-gi));
  float f_ = 1.f / (1.f + expf(-gf));
  float o_ = 1.f / (1.f + expf(-go));
  float g_ = tanhf(gg);
  float cn = f_ * ws[OFF_C0 + idx] + i_ * g_;
  ws[OFF_C0 + idx] = cn;
  ws[OFF_H0 + idx] = o_ * tanhf(cn);
}

__global__ void cell1_kernel(float* __restrict__ ws)
{
  int idx = blockIdx.x * 256 + threadIdx.x;
  int b = idx >> 10, h = idx & 1023;
  const float* bs = ws + OFF_BSUM1;
  float gi = bs[h], gf = bs[h + 1024], gg = bs[h + 2048], go = bs[h + 3072];
#pragma unroll
  for (int c = 0; c < 8; c++) {
    const float* p = ws + OFF_PART1 + ((long)c * B + b) * G4;
    gi += p[h]; gf += p[h + 1024]; gg += p[h + 2048]; go += p[h + 3072];
  }
  float i_ = 1.f / (1.f + expf(-gi));
  float f_ = 1.f / (1.f + expf(-gf));
  float o_ = 1.f / (1.f + expf(-go));
  float g_ = tanhf(gg);
  float cn = f_ * ws[OFF_C1 + idx] + i_ * g_;
  ws[OFF_C1 + idx] = cn;
  ws[OFF_H1 + idx] = o_ * tanhf(cn);
}

// ---------------- vocab projection + exp + per-wave sum/argmax ----------------
__global__ __launch_bounds__(256)
void logits_kernel(float* __restrict__ ws,
                   const float* __restrict__ Wlin,
                   const float* __restrict__ blin,
                   float* __restrict__ out, int t)
{
  __shared__ Smem sm;
  const int tid = threadIdx.x;
  const int j0  = blockIdx.x * 64;             // grid 500
  if (tid < B) sm.srow[tid] = ws + OFF_H1 + (long)tid * H;
  __syncthreads();

  float acc[8] = {};
  gemm64(Wlin, /*wcol=*/0, j0, /*xcol=*/0, /*klen=*/H, tid, sm, acc);

  const int jj = tid & 63, bg8 = (tid >> 6) << 3;
  const int j  = j0 + jj;
  const float bl = blin[j];

  float ev[8];
#pragma unroll
  for (int g = 0; g < 8; g++) {
    ev[g] = expf(acc[g] + bl);
    out[((long)(bg8 + g) * T + t) * (long)V + j] = ev[g];
  }

  // per-wave reductions over the 64 j-lanes (wave owns b = bg8..bg8+7)
  float rs[8];
  unsigned long long rm[8];
#pragma unroll
  for (int g = 0; g < 8; g++) {
    rs[g] = ev[g];
    rm[g] = ((unsigned long long)__float_as_uint(ev[g]) << 32)
          | (unsigned long long)(0xFFFFFFFFu - (unsigned)j);
  }
#pragma unroll
  for (int off = 32; off > 0; off >>= 1) {
#pragma unroll
    for (int g = 0; g < 8; g++) {
      rs[g] += __shfl_xor(rs[g], off);
      unsigned long long o = __shfl_xor(rm[g], off);
      rm[g] = o > rm[g] ? o : rm[g];
    }
  }
#pragma unroll
  for (int g = 0; g < 8; g++) {
    if (jj == g) {   // lane g of each wave commits b = bg8+g
      atomicAdd(ws + OFF_SUMS + (long)t * B + (bg8 + g), rs[g]);
      atomicMax((unsigned long long*)(ws + OFF_AMAX) + (long)t * B + (bg8 + g), rm[g]);
    }
  }
}

// ---------------- normalize ALL probs in one pass (after T loop) ----------------
__global__ void norm_all(float* __restrict__ out, const float* __restrict__ ws)
{
  int i  = blockIdx.x * 256 + threadIdx.x;   // 2048*8000 float4s
  int bt = i / 8000;                          // b*T + t
  int v4 = (i - bt * 8000) << 2;
  int b  = bt >> 6, t = bt & 63;
  float rs = 1.f / ws[OFF_SUMS + (long)t * B + b];
  float4* p = (float4*)(out + (long)bt * V + v4);
  float4 x = *p;
  x.x *= rs; x.y *= rs; x.z *= rs; x.w *= rs;
  *p = x;
}

// ---------------- host ----------------
extern "C" void kernel_launch(void* const* d_in, const int* in_sizes, int n_in,
                              void* d_out, int out_size, void* d_ws, size_t ws_size,
                              hipStream_t stream)
{
  const float* context = (const float*)d_in[0];
  // d_in[1] = max_len scalar (fixed 64, hard-coded)
  const float* emb  = (const float*)d_in[2];
  const float* Wih0 = (const float*)d_in[3];
  const float* Whh0 = (const float*)d_in[4];
  const float* bih0 = (const float*)d_in[5];
  const float* bhh0 = (const float*)d_in[6];
  const float* Wih1 = (const float*)d_in[7];
  const float* Whh1 = (const float*)d_in[8];
  const float* bih1 = (const float*)d_in[9];
  const float* bhh1 = (const float*)d_in[10];
  const float* Wlin = (const float*)d_in[11];
  const float* blin = (const float*)d_in[12];
  float* out = (float*)d_out;
  float* ws  = (float*)d_ws;

  init_kernel<<<256, 256, 0, stream>>>(ws, bih1, bhh1);
  gctx_kernel<<<64, 256, 0, stream>>>(ws, context, Wih0, bih0, bhh0);

  for (int t = 0; t < T; t++) {
    lstm_gemm<<<dim3(64, 6), 256, 0, stream>>>(0, t, Wih0, Whh0, emb, ws);
    cell0_kernel<<<128, 256, 0, stream>>>(ws);
    lstm_gemm<<<dim3(64, 8), 256, 0, stream>>>(1, t, Wih1, Whh1, emb, ws);
    cell1_kernel<<<128, 256, 0, stream>>>(ws);
    logits_kernel<<<500, 256, 0, stream>>>(ws, Wlin, blin, out, t);
  }
  norm_all<<<64000, 256, 0, stream>>>(out, ws);
}